// Round 4
// baseline (1242.750 us; speedup 1.0000x reference)
//
#include <hip/hip_runtime.h>
#include <math.h>

#define B 64
#define T 20
#define C 512
#define HW 196
#define V 10000
#define E 256
#define U 512
#define G4U 2048
#define ODIM 1280
#define KTOT 1280
#define NBLK 64   // persistent-loop grid; 64 blocks <= 256 CUs => co-resident

typedef short bf8_t __attribute__((ext_vector_type(8)));
typedef float f4_t  __attribute__((ext_vector_type(4)));

__device__ __forceinline__ unsigned short f2bf(float f) {
    unsigned int u = __float_as_uint(f);
    return (unsigned short)((u + 0x7fffu + ((u >> 16) & 1u)) >> 16);
}
__device__ __forceinline__ float bf2f(unsigned short s) {
    return __uint_as_float((unsigned int)s << 16);
}
__device__ __forceinline__ float bflo(unsigned int kv) { return __uint_as_float(kv << 16); }
__device__ __forceinline__ float bfhi(unsigned int kv) { return __uint_as_float(kv & 0xffff0000u); }

// ---- device-coherent (cross-XCD) loads/stores: sc0 sc1 bypass L1+L2, served
// at the L3 coherent point. Keeps L2 contents (img/keys2/Wg) intact.
__device__ __forceinline__ void coh_load4x2(const void* p0, const void* p1,
                                            uint4& r0, uint4& r1) {
    asm volatile("global_load_dwordx4 %0, %2, off sc0 sc1\n\t"
                 "global_load_dwordx4 %1, %3, off sc0 sc1\n\t"
                 "s_waitcnt vmcnt(0)"
                 : "=&v"(r0), "=&v"(r1) : "v"(p0), "v"(p1) : "memory");
}
__device__ __forceinline__ void coh_load4_issue(const void* p, uint4& r) {
    asm volatile("global_load_dwordx4 %0, %1, off sc0 sc1"
                 : "=&v"(r) : "v"(p) : "memory");
}
__device__ __forceinline__ void wait_vm0() {
    asm volatile("s_waitcnt vmcnt(0)" ::: "memory");
    __builtin_amdgcn_sched_barrier(0);
}
__device__ __forceinline__ void coh_store1f(void* p, float v) {
    asm volatile("global_store_dword %0, %1, off sc0 sc1" :: "v"(p), "v"(v) : "memory");
}
__device__ __forceinline__ void coh_store1u(void* p, unsigned int v) {
    asm volatile("global_store_dword %0, %1, off sc0 sc1" :: "v"(p), "v"(v) : "memory");
}
__device__ __forceinline__ void coh_store_us(void* p, unsigned int v) {
    asm volatile("global_store_short %0, %1, off sc0 sc1" :: "v"(p), "v"(v) : "memory");
}
__device__ __forceinline__ int coh_load_int(const int* p) {
    int v;
    asm volatile("global_load_dword %0, %1, off sc0 sc1\n\t"
                 "s_waitcnt vmcnt(0)"
                 : "=v"(v) : "v"(p) : "memory");
    return v;
}
__device__ __forceinline__ void coh_store_int(int* p, int v) {
    asm volatile("global_store_dword %0, %1, off sc0 sc1" :: "v"(p), "v"(v) : "memory");
}

// ---- flag-based grid barrier: per-block arrival flag on its own 64B line
// (parallel stores, no RMW serialization); block 0 wave 0 polls all 64 flags
// with 64 lanes, then bumps the generation word; others poll generation.
// barf[0]=generation; barf[16 + b*16] = flag of block b. Epoch e increases
// monotonically (no reset races).
__device__ __forceinline__ void gbarf(int* barf, int e) {
    asm volatile("s_waitcnt vmcnt(0)" ::: "memory");  // per-wave drain of data stores
    __syncthreads();                                  // all waves drained
    int tid = threadIdx.x;
    if (blockIdx.x == 0) {
        if (tid == 0) coh_store_int(barf + 16, e);    // own flag
        if (tid < 64) {
            while (!__all(coh_load_int(barf + 16 + tid * 16) >= e)) {}
            if (tid == 0) coh_store_int(barf, e);
        }
    } else {
        if (tid == 0) {
            coh_store_int(barf + 16 + blockIdx.x * 16, e);
            while (coh_load_int(barf) < e) {}
        }
    }
    __syncthreads();
}

// ---------- feats_mean ----------
__global__ void k_mean(const float* __restrict__ img, float* __restrict__ fm) {
    int wave = threadIdx.x >> 6;
    int lane = threadIdx.x & 63;
    int row = blockIdx.x * 4 + wave;
    const float* p = img + (size_t)row * HW;
    float s = p[lane] + p[lane + 64] + p[lane + 128];
    if (lane < 4) s += p[lane + 192];
    for (int off = 32; off > 0; off >>= 1) s += __shfl_down(s, off, 64);
    if (lane == 0) fm[row] = s * (1.0f / HW);
}

// ---------- hid0 -> xb (bf16) hid slot, cell0 ----------
__global__ void k_init(const float* __restrict__ fm,
                       const float* __restrict__ W_h0, const float* __restrict__ b_h0,
                       const float* __restrict__ W_c0, const float* __restrict__ b_c0,
                       unsigned short* __restrict__ xb, float* __restrict__ cell) {
    int wv = blockIdx.x * 4 + (threadIdx.x >> 6);
    int lane = threadIdx.x & 63;
    int which = wv >> 15;
    int r = wv & 32767;
    int b = r >> 9, u = r & 511;
    const float* W = which ? W_c0 : W_h0;
    const float* bias = which ? b_c0 : b_h0;
    const float* f = fm + b * C;
    const float* w = W + (size_t)u * C;
    float s = 0.f;
    #pragma unroll
    for (int c = 0; c < C; c += 64) s += f[c + lane] * w[c + lane];
    for (int off = 32; off > 0; off >>= 1) s += __shfl_down(s, off, 64);
    if (lane == 0) {
        float v = s + bias[u];
        if (which) cell[r] = v;
        else       xb[(size_t)b * KTOT + 768 + u] = f2bf(v);
    }
}

// ---------- W_keyT[c][u] ----------
__global__ void k_wkt(const float* __restrict__ Wk, float* __restrict__ WkT) {
    __shared__ float tile[64][65];
    int u0 = blockIdx.x * 64, c0 = blockIdx.y * 64;
    int x = threadIdx.x & 63, y0 = threadIdx.x >> 6;
    #pragma unroll
    for (int i = 0; i < 16; i++) {
        int r = y0 * 16 + i;
        tile[r][x] = Wk[(size_t)(u0 + r) * C + c0 + x];
    }
    __syncthreads();
    #pragma unroll
    for (int i = 0; i < 16; i++) {
        int r = y0 * 16 + i;
        WkT[(size_t)(c0 + r) * U + u0 + x] = tile[x][r];
    }
}

// ---------- keys2[b][k][u] bf16 ----------
__global__ __launch_bounds__(256) void k_keys(const float* __restrict__ img,
        const float* __restrict__ WkT, const float* __restrict__ b_key,
        unsigned short* __restrict__ keys2) {
    __shared__ unsigned short st[32][200];
    int b = blockIdx.x >> 4;
    int u0 = (blockIdx.x & 15) * 32;
    int wave = __builtin_amdgcn_readfirstlane(threadIdx.x >> 6);
    int lane = threadIdx.x & 63;
    int lk = lane < 49 ? lane : 48;
    const f4_t* imgb = (const f4_t*)(img + (size_t)b * C * HW);
    f4_t acc[8];
    #pragma unroll
    for (int j = 0; j < 8; j++) acc[j] = (f4_t){0.f, 0.f, 0.f, 0.f};
    const float* wp = WkT + u0 + wave * 8;
    for (int c = 0; c < C; c++) {
        f4_t v = imgb[c * 49 + lk];
        const float* w = wp + (size_t)c * U;
        #pragma unroll
        for (int j = 0; j < 8; j++) acc[j] += v * w[j];
    }
    if (lane < 49) {
        #pragma unroll
        for (int j = 0; j < 8; j++) {
            float bk = b_key[u0 + wave * 8 + j];
            int ul = wave * 8 + j;
            int k = lane * 4;
            st[ul][k + 0] = f2bf(acc[j].x + bk);
            st[ul][k + 1] = f2bf(acc[j].y + bk);
            st[ul][k + 2] = f2bf(acc[j].z + bk);
            st[ul][k + 3] = f2bf(acc[j].w + bk);
        }
    }
    __syncthreads();
    int ui = threadIdx.x & 15;
    int kr = threadIdx.x >> 4;
    #pragma unroll
    for (int pass = 0; pass < 13; pass++) {
        int k = pass * 16 + kr;
        if (k < HW) {
            unsigned int lo = st[ui * 2][k];
            unsigned int hi = st[ui * 2 + 1][k];
            *(unsigned int*)&keys2[((size_t)b * HW + k) * U + u0 + ui * 2] = (hi << 16) | lo;
        }
    }
}

// ---------- Wg[j][0:1280] = bf16{ W_ih[j][:], W_hh[j][:] } ----------
__global__ void k_wg(const float* __restrict__ W_ih, const float* __restrict__ W_hh,
                     unsigned short* __restrict__ Wg) {
    int j = blockIdx.x;
    int tid = threadIdx.x;
    const float* s1 = W_ih + (size_t)j * 768;
    const float* s2 = W_hh + (size_t)j * 512;
    unsigned short* dst = Wg + (size_t)j * KTOT;
    #pragma unroll
    for (int p = 0; p < 3; p++) dst[tid + p * 256] = f2bf(s1[tid + p * 256]);
    #pragma unroll
    for (int p = 0; p < 2; p++) dst[768 + tid + p * 256] = f2bf(s2[tid + p * 256]);
}

// ---------- embedding gather + renorm -> outs (bf16) emb slot; zero flags ----------
__global__ void k_emb(const int* __restrict__ ix, const float* __restrict__ emb,
                      unsigned short* __restrict__ outs, int* __restrict__ barf) {
    int bt = blockIdx.x;
    int e = threadIdx.x;
    if (bt == 0) {
        for (int i = e; i < 1040; i += 256) barf[i] = 0;
    }
    int row = ix[bt];
    float v = emb[(size_t)row * E + e];
    __shared__ float red[4];
    float sq = v * v;
    for (int off = 32; off > 0; off >>= 1) sq += __shfl_down(sq, off, 64);
    int wave = e >> 6, lane = e & 63;
    if (lane == 0) red[wave] = sq;
    __syncthreads();
    float norm = sqrtf(red[0] + red[1] + red[2] + red[3]);
    float scale = fminf(1.0f, 5.0f / fmaxf(norm, 1e-12f));
    outs[(size_t)bt * ODIM + (U + C) + e] = f2bf(v * scale);
}

// ---------- W_out f32 -> bf16 (bit-identical f2bf rounding) ----------
__global__ __launch_bounds__(256) void k_wo(const float* __restrict__ W,
                                            unsigned short* __restrict__ Wb) {
    size_t i = ((size_t)blockIdx.x * 256 + threadIdx.x) * 8;
    float4 f0 = *(const float4*)(W + i);
    float4 f1 = *(const float4*)(W + i + 4);
    uint4 q;
    q.x = ((unsigned int)f2bf(f0.y) << 16) | f2bf(f0.x);
    q.y = ((unsigned int)f2bf(f0.w) << 16) | f2bf(f0.z);
    q.z = ((unsigned int)f2bf(f1.y) << 16) | f2bf(f1.x);
    q.w = ((unsigned int)f2bf(f1.w) << 16) | f2bf(f1.z);
    *(uint4*)(Wb + i) = q;
}

// ---------- fused T-loop ----------
// gates4 layout: gates4[(b*512+u)*4 + q] so pointwise reads one dwordx4 per u.
// P2: per t, 4 stages; each stages a quarter A-panel xb[64][320] into LDS
// (batched coherent loads, XOR-swizzled ds_write), then 10 chunks of
// ds_read_b128 + plain Wg fragment loads + 2 MFMAs. Per-output K-order is
// 0,32,...,1248 — bit-identical to the previous kernel.
__global__ __launch_bounds__(256) void k_loop(
    unsigned short* __restrict__ outs, unsigned short* __restrict__ xb,
    const float* __restrict__ cell0, float* __restrict__ gates4,
    const unsigned short* __restrict__ keys2, const float* __restrict__ img,
    const float* __restrict__ b_ih, const float* __restrict__ b_hh,
    const unsigned short* __restrict__ Wg, float* __restrict__ attn,
    int* __restrict__ barf) {
    int b = blockIdx.x;
    int tid = threadIdx.x;
    int wave = __builtin_amdgcn_readfirstlane(tid >> 6);
    int lane = tid & 63;
    int m16 = lane & 15, quad = lane >> 4;
    __shared__ float hidS[U];
    __shared__ float wS[256];
    __shared__ float red[4];
    __shared__ unsigned short As[64 * 320];   // 40 KB quarter A-panel, swizzled

    // persistent per-thread state
    float c_r[2], bsum[2][4];
    #pragma unroll
    for (int p = 0; p < 2; p++) {
        int u = tid + p * 256;
        c_r[p] = cell0[(size_t)b * U + u];
        #pragma unroll
        for (int q = 0; q < 4; q++)
            bsum[p][q] = b_ih[q * 512 + u] + b_hh[q * 512 + u];
    }

    // P2 geometry: wave = m-tile (16 b-rows), 2 n-tiles of the 32-j slice.
    int j0g = blockIdx.x * 32;
    int srow = tid >> 2, scol = tid & 3;   // staging: 4 threads/row, 10 chunks each
    int arow = wave * 16 + m16;            // A fragment row for this lane
    int ep = 0;

    for (int t = 0; t <= T; ++t) {
        // ----- P1a: pointwise LSTM (t>0) or hid0 load (t==0) -----
        if (t > 0) {
            const float* g0 = gates4 + (size_t)b * 2048 + tid * 4;
            uint4 r0, r1;
            coh_load4x2(g0, g0 + 1024, r0, r1);
            #pragma unroll
            for (int p = 0; p < 2; p++) {
                int u = tid + p * 256;
                float4 gv = p ? *(float4*)&r1 : *(float4*)&r0;
                float g0f = gv.x + bsum[p][0];
                float g1f = gv.y + bsum[p][1];
                float g2f = gv.z + bsum[p][2];
                float g3f = gv.w + bsum[p][3];
                float si = 1.f / (1.f + expf(-g0f));
                float sf = 1.f / (1.f + expf(-g1f));
                float tg = tanhf(g2f);
                float so = 1.f / (1.f + expf(-g3f));
                float cn = sf * c_r[p] + si * tg;
                c_r[p] = cn;
                float hn = so * tanhf(cn);
                hidS[u] = hn;
                unsigned int hv = f2bf(hn);
                outs[((size_t)b * T + (t - 1)) * ODIM + u] = (unsigned short)hv;
                coh_store_us(&xb[(size_t)b * KTOT + 768 + u], hv);
            }
        } else {
            #pragma unroll
            for (int p = 0; p < 2; p++) {
                int u = tid + p * 256;
                hidS[u] = bf2f(xb[(size_t)b * KTOT + 768 + u]);
            }
        }
        if (t == T) break;
        __syncthreads();

        // ----- P1b: scores (thread-per-k), keys2 L2-resident -----
        float sc = 0.f;
        if (tid < HW) {
            const uint4* kr = (const uint4*)(keys2 + ((size_t)b * HW + tid) * U);
            float acc = 0.f;
            #pragma unroll 8
            for (int i = 0; i < 64; i++) {
                uint4 kv = kr[i];
                float4 h0 = *(const float4*)&hidS[i * 8];
                float4 h1 = *(const float4*)&hidS[i * 8 + 4];
                acc += bflo(kv.x) * h0.x + bfhi(kv.x) * h0.y
                     + bflo(kv.y) * h0.z + bfhi(kv.y) * h0.w
                     + bflo(kv.z) * h1.x + bfhi(kv.z) * h1.y
                     + bflo(kv.w) * h1.z + bfhi(kv.w) * h1.w;
            }
            sc = acc * 0.044194173824159216f;
        }
        // ----- softmax over 196 -----
        {
            float v = (tid < HW) ? sc : -1e30f;
            float m = v;
            for (int off = 32; off > 0; off >>= 1) m = fmaxf(m, __shfl_down(m, off, 64));
            if (lane == 0) red[wave] = m;
            __syncthreads();
            m = fmaxf(fmaxf(red[0], red[1]), fmaxf(red[2], red[3]));
            float ex = (tid < HW) ? expf(v - m) : 0.f;
            float ssum = ex;
            for (int off = 32; off > 0; off >>= 1) ssum += __shfl_down(ssum, off, 64);
            __syncthreads();
            if (lane == 0) red[wave] = ssum;
            __syncthreads();
            ssum = red[0] + red[1] + red[2] + red[3];
            float w = ex / ssum;
            wS[tid] = w;
            if (tid < HW) attn[((size_t)b * T + t) * HW + tid] = w;
        }
        __syncthreads();

        // ----- P1c: context (thread-per-c), img L2-resident -----
        {
            const float4* imgb = (const float4*)(img + (size_t)b * C * HW);
            #pragma unroll
            for (int p = 0; p < 2; p++) {
                int c = tid + p * 256;
                const float4* rr4 = imgb + c * 49;
                float acc = 0.f;
                for (int k4 = 0; k4 < 49; k4++) {
                    float4 vv = rr4[k4];
                    acc += wS[4 * k4] * vv.x + wS[4 * k4 + 1] * vv.y
                         + wS[4 * k4 + 2] * vv.z + wS[4 * k4 + 3] * vv.w;
                }
                unsigned int av = f2bf(acc);
                coh_store_us(&xb[(size_t)b * KTOT + 256 + c], av);
                outs[((size_t)b * T + t) * ODIM + U + c] = (unsigned short)av;
            }
        }
        // emb (bf16) -> xb via coherent uint copy
        if (tid < 128) {
            const unsigned int* src = (const unsigned int*)(outs + ((size_t)b * T + t) * ODIM);
            unsigned int* dst = (unsigned int*)(xb + (size_t)b * KTOT);
            coh_store1u(&dst[tid], src[512 + tid]);
        }

        ++ep; gbarf(barf, ep);   // xb complete (all b) -> GEMM may read

        // ----- P2: gates GEMM, block owns j in [j0g, j0g+32) for all 64 b -----
        {
            f4_t acc2[2];
            acc2[0] = (f4_t){0.f, 0.f, 0.f, 0.f};
            acc2[1] = (f4_t){0.f, 0.f, 0.f, 0.f};
            #pragma unroll 1
            for (int s = 0; s < 4; s++) {
                int kbase = s * 320;
                // stage quarter A-panel: 10 batched coherent 16B loads/thread
                uint4 ra[10];
                #pragma unroll
                for (int p = 0; p < 10; p++)
                    coh_load4_issue(&xb[(size_t)srow * KTOT + kbase + (scol + 4 * p) * 8], ra[p]);
                wait_vm0();
                #pragma unroll
                for (int p = 0; p < 10; p++) {
                    int chunk = scol + 4 * p;
                    *(uint4*)&As[srow * 320 + ((chunk * 8) ^ ((srow & 7) << 3))] = ra[p];
                }
                __syncthreads();
                #pragma unroll
                for (int c = 0; c < 10; c++) {
                    int kl = c * 32 + quad * 8;
                    bf8_t afr = *(const bf8_t*)&As[arow * 320 + (kl ^ ((m16 & 7) << 3))];
                    int kg = kbase + kl;
                    bf8_t b0 = *(const bf8_t*)&Wg[(size_t)(j0g + m16) * KTOT + kg];
                    bf8_t b1 = *(const bf8_t*)&Wg[(size_t)(j0g + 16 + m16) * KTOT + kg];
                    acc2[0] = __builtin_amdgcn_mfma_f32_16x16x32_bf16(afr, b0, acc2[0], 0, 0, 0);
                    acc2[1] = __builtin_amdgcn_mfma_f32_16x16x32_bf16(afr, b1, acc2[1], 0, 0, 0);
                }
                __syncthreads();
            }
            #pragma unroll
            for (int nt = 0; nt < 2; nt++) {
                int n = j0g + nt * 16 + m16;
                int qq = n >> 9, uu = n & 511;
                #pragma unroll
                for (int rr = 0; rr < 4; rr++) {
                    int bb = wave * 16 + quad * 4 + rr;
                    coh_store1f(&gates4[((size_t)bb * 512 + uu) * 4 + qq], acc2[nt][rr]);
                }
            }
        }

        ++ep; gbarf(barf, ep);   // gates complete -> next pointwise may read
    }
}

// ---------- logits: bf16 MFMA, f32 B with in-kernel convert (fallback) ----------
__global__ __launch_bounds__(256) void k_logits4(
    const unsigned short* __restrict__ A, const float* __restrict__ Wo,
    const float* __restrict__ bo, float* __restrict__ Cout) {
    __shared__ unsigned short As[128][72];
    __shared__ unsigned short Bs[128][72];
    int n0 = blockIdx.x * 128;
    int m0 = blockIdx.y * 128;
    int tid = threadIdx.x;
    int lane = tid & 63, wv = tid >> 6;
    int mw = (wv >> 1) * 64, nw = (wv & 1) * 64;
    int m16 = lane & 15, quad = lane >> 4;
    int srow = tid >> 1, shalf = tid & 1;

    f4_t acc[4][4];
    #pragma unroll
    for (int i = 0; i < 4; i++)
        #pragma unroll
        for (int j = 0; j < 4; j++)
            acc[i][j] = (f4_t){0.f, 0.f, 0.f, 0.f};

    for (int k0 = 0; k0 < KTOT; k0 += 64) {
        {
            const uint4* ap = (const uint4*)&A[(size_t)(m0 + srow) * KTOT + k0 + shalf * 32];
            uint4 a0 = ap[0], a1 = ap[1], a2 = ap[2], a3 = ap[3];
            uint4* dst = (uint4*)&As[srow][shalf * 32];
            dst[0] = a0; dst[1] = a1; dst[2] = a2; dst[3] = a3;
        }
        {
            int n = n0 + srow;
            uint4 q[4];
            if (n < V) {
                const float4* bp = (const float4*)&Wo[(size_t)n * KTOT + k0 + shalf * 32];
                #pragma unroll
                for (int g = 0; g < 4; g++) {
                    float4 f0 = bp[g * 2], f1 = bp[g * 2 + 1];
                    q[g].x = ((unsigned int)f2bf(f0.y) << 16) | f2bf(f0.x);
                    q[g].y = ((unsigned int)f2bf(f0.w) << 16) | f2bf(f0.z);
                    q[g].z = ((unsigned int)f2bf(f1.y) << 16) | f2bf(f1.x);
                    q[g].w = ((unsigned int)f2bf(f1.w) << 16) | f2bf(f1.z);
                }
            } else {
                #pragma unroll
                for (int g = 0; g < 4; g++) q[g] = (uint4){0u, 0u, 0u, 0u};
            }
            uint4* dst = (uint4*)&Bs[srow][shalf * 32];
            #pragma unroll
            for (int g = 0; g < 4; g++) dst[g] = q[g];
        }
        __syncthreads();
        #pragma unroll
        for (int h = 0; h < 2; h++) {
            bf8_t af[4], bf[4];
            #pragma unroll
            for (int i = 0; i < 4; i++)
                af[i] = *(const bf8_t*)&As[mw + i * 16 + m16][h * 32 + quad * 8];
            #pragma unroll
            for (int j = 0; j < 4; j++)
                bf[j] = *(const bf8_t*)&Bs[nw + j * 16 + m16][h * 32 + quad * 8];
            #pragma unroll
            for (int i = 0; i < 4; i++)
                #pragma unroll
                for (int j = 0; j < 4; j++)
                    acc[i][j] = __builtin_amdgcn_mfma_f32_16x16x32_bf16(af[i], bf[j], acc[i][j], 0, 0, 0);
        }
        __syncthreads();
    }

    #pragma unroll
    for (int j = 0; j < 4; j++) {
        int n = n0 + nw + j * 16 + m16;
        if (n >= V) continue;
        float bias = bo[n];
        #pragma unroll
        for (int i = 0; i < 4; i++) {
            int mb = m0 + mw + i * 16 + quad * 4;
            #pragma unroll
            for (int r = 0; r < 4; r++)
                Cout[(size_t)(mb + r) * V + n] = acc[i][j][r] + bias;
        }
    }
}

// ---------- logits: bf16 MFMA with pre-converted bf16 B ----------
__global__ __launch_bounds__(256) void k_logits5(
    const unsigned short* __restrict__ A, const unsigned short* __restrict__ Wob,
    const float* __restrict__ bo, float* __restrict__ Cout) {
    __shared__ unsigned short As[128][72];
    __shared__ unsigned short Bs[128][72];
    int n0 = blockIdx.x * 128;
    int m0 = blockIdx.y * 128;
    int tid = threadIdx.x;
    int lane = tid & 63, wv = tid >> 6;
    int mw = (wv >> 1) * 64, nw = (wv & 1) * 64;
    int m16 = lane & 15, quad = lane >> 4;
    int srow = tid >> 1, shalf = tid & 1;

    f4_t acc[4][4];
    #pragma unroll
    for (int i = 0; i < 4; i++)
        #pragma unroll
        for (int j = 0; j < 4; j++)
            acc[i][j] = (f4_t){0.f, 0.f, 0.f, 0.f};

    for (int k0 = 0; k0 < KTOT; k0 += 64) {
        {
            const uint4* ap = (const uint4*)&A[(size_t)(m0 + srow) * KTOT + k0 + shalf * 32];
            uint4 a0 = ap[0], a1 = ap[1], a2 = ap[2], a3 = ap[3];
            uint4* dst = (uint4*)&As[srow][shalf * 32];
            dst[0] = a0; dst[1] = a1; dst[2] = a2; dst[3] = a3;
        }
        {
            int n = n0 + srow;
            uint4 q[4];
            if (n < V) {
                const uint4* bp = (const uint4*)&Wob[(size_t)n * KTOT + k0 + shalf * 32];
                #pragma unroll
                for (int g = 0; g < 4; g++) q[g] = bp[g];
            } else {
                #pragma unroll
                for (int g = 0; g < 4; g++) q[g] = (uint4){0u, 0u, 0u, 0u};
            }
            uint4* dst = (uint4*)&Bs[srow][shalf * 32];
            #pragma unroll
            for (int g = 0; g < 4; g++) dst[g] = q[g];
        }
        __syncthreads();
        #pragma unroll
        for (int h = 0; h < 2; h++) {
            bf8_t af[4], bf[4];
            #pragma unroll
            for (int i = 0; i < 4; i++)
                af[i] = *(const bf8_t*)&As[mw + i * 16 + m16][h * 32 + quad * 8];
            #pragma unroll
            for (int j = 0; j < 4; j++)
                bf[j] = *(const bf8_t*)&Bs[nw + j * 16 + m16][h * 32 + quad * 8];
            #pragma unroll
            for (int i = 0; i < 4; i++)
                #pragma unroll
                for (int j = 0; j < 4; j++)
                    acc[i][j] = __builtin_amdgcn_mfma_f32_16x16x32_bf16(af[i], bf[j], acc[i][j], 0, 0, 0);
        }
        __syncthreads();
    }

    #pragma unroll
    for (int j = 0; j < 4; j++) {
        int n = n0 + nw + j * 16 + m16;
        if (n >= V) continue;
        float bias = bo[n];
        #pragma unroll
        for (int i = 0; i < 4; i++) {
            int mb = m0 + mw + i * 16 + quad * 4;
            #pragma unroll
            for (int r = 0; r < 4; r++)
                Cout[(size_t)(mb + r) * V + n] = acc[i][j][r] + bias;
        }
    }
}

extern "C" void kernel_launch(void* const* d_in, const int* in_sizes, int n_in,
                              void* d_out, int out_size, void* d_ws, size_t ws_size,
                              hipStream_t stream) {
    const float* img   = (const float*)d_in[0];
    const int*   capix = (const int*)d_in[1];
    const float* W_h0  = (const float*)d_in[2];
    const float* b_h0  = (const float*)d_in[3];
    const float* W_c0  = (const float*)d_in[4];
    const float* b_c0  = (const float*)d_in[5];
    const float* emb   = (const float*)d_in[6];
    const float* W_key = (const float*)d_in[7];
    const float* b_key = (const float*)d_in[8];
    const float* W_ih  = (const float*)d_in[9];
    const float* b_ih  = (const float*)d_in[10];
    const float* W_hh  = (const float*)d_in[11];
    const float* b_hh  = (const float*)d_in[12];
    const float* W_out = (const float*)d_in[13];
    const float* b_out = (const float*)d_in[14];

    float* ws = (float*)d_ws;
    float* gates4    = ws;                        // 131072 f (fm overlaid)
    float* fm        = ws;                        // 32768 f, dead before t=0 gates
    float* cell      = gates4 + 131072;           // 32768 f
    float* WkT       = cell + 32768;              // 262144 f; dead after k_keys ->
    int*   barf      = (int*)WkT;                 //   reused as barrier flags (1040 ints)
    unsigned short* Wg    = (unsigned short*)(WkT + 262144);  // 2621440 ush
    unsigned short* xb    = Wg + 2621440;                      // 81920 ush
    unsigned short* outs  = xb + 81920;                        // 1638400 ush
    unsigned short* keys2 = outs + (size_t)B * T * ODIM;       // 6422528 ush
    const size_t WOB_OFF = 23232576;                           // 64B-aligned
    unsigned short* Wob = (unsigned short*)((char*)d_ws + WOB_OFF);
    bool use_wob = ws_size >= WOB_OFF + (size_t)V * KTOT * 2;  // need 48,832,576 B

    float* logits = (float*)d_out;
    float* attn   = logits + (size_t)B * T * V;

    k_mean<<<(B * C) / 4, 256, 0, stream>>>(img, fm);
    k_init<<<(2 * B * U) / 4, 256, 0, stream>>>(fm, W_h0, b_h0, W_c0, b_c0, xb, cell);
    k_wkt<<<dim3(8, 8), 256, 0, stream>>>(W_key, WkT);
    k_keys<<<B * 16, 256, 0, stream>>>(img, WkT, b_key, keys2);
    k_wg<<<G4U, 256, 0, stream>>>(W_ih, W_hh, Wg);
    k_emb<<<B * T, 256, 0, stream>>>(capix, emb, outs, barf);
    if (use_wob)
        k_wo<<<(V * KTOT) / 2048, 256, 0, stream>>>(W_out, Wob);

    k_loop<<<NBLK, 256, 0, stream>>>(outs, xb, cell, gates4, keys2, img,
                                     b_ih, b_hh, Wg, attn, barf);

    if (use_wob)
        k_logits5<<<dim3((V + 127) / 128, (B * T) / 128), 256, 0, stream>>>(outs, Wob, b_out, logits);
    else
        k_logits4<<<dim3((V + 127) / 128, (B * T) / 128), 256, 0, stream>>>(outs, W_out, b_out, logits);
}

// Round 5
// 1179.365 us; speedup vs baseline: 1.0537x; 1.0537x over previous
//
#include <hip/hip_runtime.h>
#include <math.h>

#define B 64
#define T 20
#define C 512
#define HW 196
#define V 10000
#define E 256
#define U 512
#define G4U 2048
#define ODIM 1280
#define KTOT 1280
#define NBLK 64   // persistent-loop grid; 64 blocks <= 256 CUs => co-resident

typedef short bf8_t __attribute__((ext_vector_type(8)));
typedef float f4_t  __attribute__((ext_vector_type(4)));
typedef _Float16 h2_t __attribute__((ext_vector_type(2)));

__device__ __forceinline__ unsigned short f2bf(float f) {
    unsigned int u = __float_as_uint(f);
    return (unsigned short)((u + 0x7fffu + ((u >> 16) & 1u)) >> 16);
}
__device__ __forceinline__ float bf2f(unsigned short s) {
    return __uint_as_float((unsigned int)s << 16);
}
__device__ __forceinline__ float bflo(unsigned int kv) { return __uint_as_float(kv << 16); }
__device__ __forceinline__ float bfhi(unsigned int kv) { return __uint_as_float(kv & 0xffff0000u); }
__device__ __forceinline__ unsigned short f2h(float f) {
    _Float16 h = (_Float16)f;
    return *(unsigned short*)&h;
}

// ---- device-coherent (cross-XCD) loads/stores: sc0 sc1 bypass L1+L2, served
// at the L3 coherent point. Keeps L2 contents (img2/keys2/Wg) intact.
__device__ __forceinline__ void coh_load4w(const void* p, uint4& r) {
    asm volatile("global_load_dwordx4 %0, %1, off sc0 sc1\n\t"
                 "s_waitcnt vmcnt(0)"
                 : "=&v"(r) : "v"(p) : "memory");
}
__device__ __forceinline__ void coh_load4_issue(const void* p, uint4& r) {
    asm volatile("global_load_dwordx4 %0, %1, off sc0 sc1"
                 : "=&v"(r) : "v"(p) : "memory");
}
__device__ __forceinline__ void wait_vm0() {
    asm volatile("s_waitcnt vmcnt(0)" ::: "memory");
    __builtin_amdgcn_sched_barrier(0);
}
__device__ __forceinline__ void coh_store1f(void* p, float v) {
    asm volatile("global_store_dword %0, %1, off sc0 sc1" :: "v"(p), "v"(v) : "memory");
}
__device__ __forceinline__ void coh_store1u(void* p, unsigned int v) {
    asm volatile("global_store_dword %0, %1, off sc0 sc1" :: "v"(p), "v"(v) : "memory");
}
__device__ __forceinline__ void coh_store_us(void* p, unsigned int v) {
    asm volatile("global_store_short %0, %1, off sc0 sc1" :: "v"(p), "v"(v) : "memory");
}
__device__ __forceinline__ int coh_load_int(const int* p) {
    int v;
    asm volatile("global_load_dword %0, %1, off sc0 sc1\n\t"
                 "s_waitcnt vmcnt(0)"
                 : "=v"(v) : "v"(p) : "memory");
    return v;
}
__device__ __forceinline__ void coh_store_int(int* p, int v) {
    asm volatile("global_store_dword %0, %1, off sc0 sc1" :: "v"(p), "v"(v) : "memory");
}

// ---- flag-based grid barrier: per-block arrival flag on its own 64B line;
// block 0 wave 0 polls all 64 flags, bumps generation; others poll generation.
__device__ __forceinline__ void gbarf(int* barf, int e) {
    asm volatile("s_waitcnt vmcnt(0)" ::: "memory");
    __syncthreads();
    int tid = threadIdx.x;
    if (blockIdx.x == 0) {
        if (tid == 0) coh_store_int(barf + 16, e);
        if (tid < 64) {
            while (!__all(coh_load_int(barf + 16 + tid * 16) >= e)) {}
            if (tid == 0) coh_store_int(barf, e);
        }
    } else {
        if (tid == 0) {
            coh_store_int(barf + 16 + blockIdx.x * 16, e);
            while (coh_load_int(barf) < e) {}
        }
    }
    __syncthreads();
}

// ---------- feats_mean ----------
__global__ void k_mean(const float* __restrict__ img, float* __restrict__ fm) {
    int wave = threadIdx.x >> 6;
    int lane = threadIdx.x & 63;
    int row = blockIdx.x * 4 + wave;
    const float* p = img + (size_t)row * HW;
    float s = p[lane] + p[lane + 64] + p[lane + 128];
    if (lane < 4) s += p[lane + 192];
    for (int off = 32; off > 0; off >>= 1) s += __shfl_down(s, off, 64);
    if (lane == 0) fm[row] = s * (1.0f / HW);
}

// ---------- hid0 -> xb (bf16) hid slot, cell0 ----------
__global__ void k_init(const float* __restrict__ fm,
                       const float* __restrict__ W_h0, const float* __restrict__ b_h0,
                       const float* __restrict__ W_c0, const float* __restrict__ b_c0,
                       unsigned short* __restrict__ xb, float* __restrict__ cell) {
    int wv = blockIdx.x * 4 + (threadIdx.x >> 6);
    int lane = threadIdx.x & 63;
    int which = wv >> 15;
    int r = wv & 32767;
    int b = r >> 9, u = r & 511;
    const float* W = which ? W_c0 : W_h0;
    const float* bias = which ? b_c0 : b_h0;
    const float* f = fm + b * C;
    const float* w = W + (size_t)u * C;
    float s = 0.f;
    #pragma unroll
    for (int c = 0; c < C; c += 64) s += f[c + lane] * w[c + lane];
    for (int off = 32; off > 0; off >>= 1) s += __shfl_down(s, off, 64);
    if (lane == 0) {
        float v = s + bias[u];
        if (which) cell[r] = v;
        else       xb[(size_t)b * KTOT + 768 + u] = f2bf(v);
    }
}

// ---------- W_keyT[c][u] ----------
__global__ void k_wkt(const float* __restrict__ Wk, float* __restrict__ WkT) {
    __shared__ float tile[64][65];
    int u0 = blockIdx.x * 64, c0 = blockIdx.y * 64;
    int x = threadIdx.x & 63, y0 = threadIdx.x >> 6;
    #pragma unroll
    for (int i = 0; i < 16; i++) {
        int r = y0 * 16 + i;
        tile[r][x] = Wk[(size_t)(u0 + r) * C + c0 + x];
    }
    __syncthreads();
    #pragma unroll
    for (int i = 0; i < 16; i++) {
        int r = y0 * 16 + i;
        WkT[(size_t)(c0 + r) * U + u0 + x] = tile[x][r];
    }
}

// ---------- keys2[b][k][u] bf16 ----------
__global__ __launch_bounds__(256) void k_keys(const float* __restrict__ img,
        const float* __restrict__ WkT, const float* __restrict__ b_key,
        unsigned short* __restrict__ keys2) {
    __shared__ unsigned short st[32][200];
    int b = blockIdx.x >> 4;
    int u0 = (blockIdx.x & 15) * 32;
    int wave = __builtin_amdgcn_readfirstlane(threadIdx.x >> 6);
    int lane = threadIdx.x & 63;
    int lk = lane < 49 ? lane : 48;
    const f4_t* imgb = (const f4_t*)(img + (size_t)b * C * HW);
    f4_t acc[8];
    #pragma unroll
    for (int j = 0; j < 8; j++) acc[j] = (f4_t){0.f, 0.f, 0.f, 0.f};
    const float* wp = WkT + u0 + wave * 8;
    for (int c = 0; c < C; c++) {
        f4_t v = imgb[c * 49 + lk];
        const float* w = wp + (size_t)c * U;
        #pragma unroll
        for (int j = 0; j < 8; j++) acc[j] += v * w[j];
    }
    if (lane < 49) {
        #pragma unroll
        for (int j = 0; j < 8; j++) {
            float bk = b_key[u0 + wave * 8 + j];
            int ul = wave * 8 + j;
            int k = lane * 4;
            st[ul][k + 0] = f2bf(acc[j].x + bk);
            st[ul][k + 1] = f2bf(acc[j].y + bk);
            st[ul][k + 2] = f2bf(acc[j].z + bk);
            st[ul][k + 3] = f2bf(acc[j].w + bk);
        }
    }
    __syncthreads();
    int ui = threadIdx.x & 15;
    int kr = threadIdx.x >> 4;
    #pragma unroll
    for (int pass = 0; pass < 13; pass++) {
        int k = pass * 16 + kr;
        if (k < HW) {
            unsigned int lo = st[ui * 2][k];
            unsigned int hi = st[ui * 2 + 1][k];
            *(unsigned int*)&keys2[((size_t)b * HW + k) * U + u0 + ui * 2] = (hi << 16) | lo;
        }
    }
}

// ---------- Wg[j][0:1280] = bf16{ W_ih[j][:], W_hh[j][:] } ----------
__global__ void k_wg(const float* __restrict__ W_ih, const float* __restrict__ W_hh,
                     unsigned short* __restrict__ Wg) {
    int j = blockIdx.x;
    int tid = threadIdx.x;
    const float* s1 = W_ih + (size_t)j * 768;
    const float* s2 = W_hh + (size_t)j * 512;
    unsigned short* dst = Wg + (size_t)j * KTOT;
    #pragma unroll
    for (int p = 0; p < 3; p++) dst[tid + p * 256] = f2bf(s1[tid + p * 256]);
    #pragma unroll
    for (int p = 0; p < 2; p++) dst[768 + tid + p * 256] = f2bf(s2[tid + p * 256]);
}

// ---------- embedding gather + renorm -> outs (bf16) emb slot; zero flags ----------
__global__ void k_emb(const int* __restrict__ ix, const float* __restrict__ emb,
                      unsigned short* __restrict__ outs, int* __restrict__ barf) {
    int bt = blockIdx.x;
    int e = threadIdx.x;
    if (bt == 0) {
        for (int i = e; i < 1040; i += 256) barf[i] = 0;
    }
    int row = ix[bt];
    float v = emb[(size_t)row * E + e];
    __shared__ float red[4];
    float sq = v * v;
    for (int off = 32; off > 0; off >>= 1) sq += __shfl_down(sq, off, 64);
    int wave = e >> 6, lane = e & 63;
    if (lane == 0) red[wave] = sq;
    __syncthreads();
    float norm = sqrtf(red[0] + red[1] + red[2] + red[3]);
    float scale = fminf(1.0f, 5.0f / fmaxf(norm, 1e-12f));
    outs[(size_t)bt * ODIM + (U + C) + e] = f2bf(v * scale);
}

// ---------- img f32 -> fp16, rows padded to 200 ----------
__global__ __launch_bounds__(256) void k_img(const float* __restrict__ img,
                                             unsigned short* __restrict__ img2) {
    int oid = blockIdx.x * 256 + threadIdx.x;   // 0..819199
    int row = oid / 25, p = oid - row * 25;
    const float* src = img + (size_t)row * HW;
    unsigned short h[8];
    #pragma unroll
    for (int i = 0; i < 8; i++) {
        int k = p * 8 + i;
        float f = (k < HW) ? src[k] : 0.f;
        h[i] = f2h(f);
    }
    *(uint4*)&img2[(size_t)row * 200 + p * 8] = *(const uint4*)h;
}

// ---------- W_out f32 -> bf16 ----------
__global__ __launch_bounds__(256) void k_wo(const float* __restrict__ W,
                                            unsigned short* __restrict__ Wb) {
    size_t i = ((size_t)blockIdx.x * 256 + threadIdx.x) * 8;
    float4 f0 = *(const float4*)(W + i);
    float4 f1 = *(const float4*)(W + i + 4);
    uint4 q;
    q.x = ((unsigned int)f2bf(f0.y) << 16) | f2bf(f0.x);
    q.y = ((unsigned int)f2bf(f0.w) << 16) | f2bf(f0.z);
    q.z = ((unsigned int)f2bf(f1.y) << 16) | f2bf(f1.x);
    q.w = ((unsigned int)f2bf(f1.w) << 16) | f2bf(f1.z);
    *(uint4*)(Wb + i) = q;
}

// ---------- fused T-loop, 512 threads (8 waves/CU) ----------
__global__ __launch_bounds__(512) void k_loop(
    unsigned short* __restrict__ outs, unsigned short* __restrict__ xb,
    const float* __restrict__ cell0, float* __restrict__ gates4,
    const unsigned short* __restrict__ keys2, const float* __restrict__ img,
    const unsigned short* __restrict__ img2,
    const float* __restrict__ b_ih, const float* __restrict__ b_hh,
    const unsigned short* __restrict__ Wg, float* __restrict__ attn,
    int* __restrict__ barf) {
    int b = blockIdx.x;
    int tid = threadIdx.x;
    int wave = __builtin_amdgcn_readfirstlane(tid >> 6);
    int lane = tid & 63;
    int m16 = lane & 15, quad = lane >> 4;
    __shared__ float hidS[U];
    __shared__ float wS[200];
    __shared__ float red[8];
    __shared__ __align__(16) unsigned int wH[100];
    __shared__ unsigned short As[64 * 320];   // 40 KB quarter A-panel, swizzled

    // persistent per-thread state: one u per thread
    float c_r = cell0[(size_t)b * U + tid];
    float bsum[4];
    #pragma unroll
    for (int q = 0; q < 4; q++)
        bsum[q] = b_ih[q * 512 + tid] + b_hh[q * 512 + tid];

    // P2 geometry: wave -> (m-tile, n-tile) of the 64x32 output
    int j0g = b * 32;
    int mt = wave >> 1, nt = wave & 1;
    int arow = mt * 16 + m16;
    int srow = tid >> 3, sc8 = tid & 7;   // staging: 8 threads/row, 5 chunks each
    int ep = 0;

    for (int t = 0; t <= T; ++t) {
        // ----- P1a: pointwise LSTM (t>0) or hid0 load (t==0) -----
        if (t > 0) {
            uint4 r0;
            coh_load4w(gates4 + ((size_t)b * 512 + tid) * 4, r0);
            float4 gv = *(float4*)&r0;
            float g0f = gv.x + bsum[0];
            float g1f = gv.y + bsum[1];
            float g2f = gv.z + bsum[2];
            float g3f = gv.w + bsum[3];
            float si = 1.f / (1.f + expf(-g0f));
            float sf = 1.f / (1.f + expf(-g1f));
            float tg = tanhf(g2f);
            float so = 1.f / (1.f + expf(-g3f));
            float cn = sf * c_r + si * tg;
            c_r = cn;
            float hn = so * tanhf(cn);
            hidS[tid] = hn;
            unsigned int hv = f2bf(hn);
            outs[((size_t)b * T + (t - 1)) * ODIM + tid] = (unsigned short)hv;
            coh_store_us(&xb[(size_t)b * KTOT + 768 + tid], hv);
        } else {
            hidS[tid] = bf2f(xb[(size_t)b * KTOT + 768 + tid]);
        }
        if (t == T) break;
        __syncthreads();

        // ----- P1b: scores (thread-per-k), keys2 L2-resident -----
        float sc = 0.f;
        if (tid < HW) {
            const uint4* kr = (const uint4*)(keys2 + ((size_t)b * HW + tid) * U);
            float acc = 0.f;
            #pragma unroll 8
            for (int i = 0; i < 64; i++) {
                uint4 kv = kr[i];
                float4 h0 = *(const float4*)&hidS[i * 8];
                float4 h1 = *(const float4*)&hidS[i * 8 + 4];
                acc += bflo(kv.x) * h0.x + bfhi(kv.x) * h0.y
                     + bflo(kv.y) * h0.z + bfhi(kv.y) * h0.w
                     + bflo(kv.z) * h1.x + bfhi(kv.z) * h1.y
                     + bflo(kv.w) * h1.z + bfhi(kv.w) * h1.w;
            }
            sc = acc * 0.044194173824159216f;
        }
        // ----- softmax over 196 (8 waves) -----
        {
            float v = (tid < HW) ? sc : -1e30f;
            float m = v;
            for (int off = 32; off > 0; off >>= 1) m = fmaxf(m, __shfl_down(m, off, 64));
            if (lane == 0) red[wave] = m;
            __syncthreads();
            m = red[0];
            #pragma unroll
            for (int i = 1; i < 8; i++) m = fmaxf(m, red[i]);
            float ex = (tid < HW) ? expf(v - m) : 0.f;
            float ssum = ex;
            for (int off = 32; off > 0; off >>= 1) ssum += __shfl_down(ssum, off, 64);
            __syncthreads();
            if (lane == 0) red[wave] = ssum;
            __syncthreads();
            ssum = red[0];
            #pragma unroll
            for (int i = 1; i < 8; i++) ssum += red[i];
            float w = ex / ssum;
            if (tid < HW) {
                wS[tid] = w;
                attn[((size_t)b * T + t) * HW + tid] = w;
            } else if (tid < 200) {
                wS[tid] = 0.f;
            }
        }
        __syncthreads();
        if (tid < 100) {
            unsigned int lo = f2h(wS[2 * tid]);
            unsigned int hi = f2h(wS[2 * tid + 1]);
            wH[tid] = (hi << 16) | lo;
        }
        __syncthreads();

        // ----- P1c: context (thread-per-c) -----
        {
            float acc = 0.f;
            if (img2) {
                const uint4* rowp = (const uint4*)(img2 + ((size_t)b * 512 + tid) * 200);
                const uint4* w4 = (const uint4*)wH;
                #pragma unroll
                for (int p = 0; p < 25; p++) {
                    uint4 v = rowp[p];
                    uint4 wv = w4[p];
                    const h2_t* va = (const h2_t*)&v;
                    const h2_t* wa = (const h2_t*)&wv;
#if __has_builtin(__builtin_amdgcn_fdot2)
                    acc = __builtin_amdgcn_fdot2(va[0], wa[0], acc, false);
                    acc = __builtin_amdgcn_fdot2(va[1], wa[1], acc, false);
                    acc = __builtin_amdgcn_fdot2(va[2], wa[2], acc, false);
                    acc = __builtin_amdgcn_fdot2(va[3], wa[3], acc, false);
#else
                    #pragma unroll
                    for (int q = 0; q < 4; q++) {
                        acc += (float)va[q][0] * (float)wa[q][0];
                        acc += (float)va[q][1] * (float)wa[q][1];
                    }
#endif
                }
            } else {
                const float4* rr4 = (const float4*)(img + (size_t)b * C * HW) + tid * 49;
                for (int k4 = 0; k4 < 49; k4++) {
                    float4 vv = rr4[k4];
                    acc += wS[4 * k4] * vv.x + wS[4 * k4 + 1] * vv.y
                         + wS[4 * k4 + 2] * vv.z + wS[4 * k4 + 3] * vv.w;
                }
            }
            unsigned int av = f2bf(acc);
            coh_store_us(&xb[(size_t)b * KTOT + 256 + tid], av);
            outs[((size_t)b * T + t) * ODIM + U + tid] = (unsigned short)av;
        }
        // emb (bf16) -> xb via coherent uint copy
        if (tid < 128) {
            const unsigned int* src = (const unsigned int*)(outs + ((size_t)b * T + t) * ODIM);
            unsigned int* dst = (unsigned int*)(xb + (size_t)b * KTOT);
            coh_store1u(&dst[tid], src[512 + tid]);
        }

        ++ep; gbarf(barf, ep);   // xb complete (all b) -> GEMM may read

        // ----- P2: gates GEMM, block owns j in [j0g, j0g+32) for all 64 b -----
        {
            f4_t acc2 = (f4_t){0.f, 0.f, 0.f, 0.f};
            #pragma unroll 1
            for (int s = 0; s < 4; s++) {
                int kbase = s * 320;
                uint4 ra[5];
                #pragma unroll
                for (int p = 0; p < 5; p++) {
                    int chunk = sc8 + 8 * p;
                    coh_load4_issue(&xb[(size_t)srow * KTOT + kbase + chunk * 8], ra[p]);
                }
                wait_vm0();
                #pragma unroll
                for (int p = 0; p < 5; p++) {
                    int chunk = sc8 + 8 * p;
                    *(uint4*)&As[srow * 320 + ((chunk * 8) ^ ((srow & 7) << 3))] = ra[p];
                }
                __syncthreads();
                #pragma unroll
                for (int c = 0; c < 10; c++) {
                    int kl = c * 32 + quad * 8;
                    bf8_t afr = *(const bf8_t*)&As[arow * 320 + (kl ^ ((arow & 7) << 3))];
                    int kg = kbase + kl;
                    bf8_t bfr = *(const bf8_t*)&Wg[(size_t)(j0g + nt * 16 + m16) * KTOT + kg];
                    acc2 = __builtin_amdgcn_mfma_f32_16x16x32_bf16(afr, bfr, acc2, 0, 0, 0);
                }
                __syncthreads();
            }
            int n = j0g + nt * 16 + m16;
            int qq = n >> 9, uu = n & 511;
            #pragma unroll
            for (int rr = 0; rr < 4; rr++) {
                int bb = mt * 16 + quad * 4 + rr;
                coh_store1f(&gates4[((size_t)bb * 512 + uu) * 4 + qq], acc2[rr]);
            }
        }

        ++ep; gbarf(barf, ep);   // gates complete -> next pointwise may read
    }
}

// ---------- logits: bf16 MFMA, f32 B with in-kernel convert (fallback) ----------
__global__ __launch_bounds__(256) void k_logits4(
    const unsigned short* __restrict__ A, const float* __restrict__ Wo,
    const float* __restrict__ bo, float* __restrict__ Cout) {
    __shared__ unsigned short As[128][72];
    __shared__ unsigned short Bs[128][72];
    int n0 = blockIdx.x * 128;
    int m0 = blockIdx.y * 128;
    int tid = threadIdx.x;
    int lane = tid & 63, wv = tid >> 6;
    int mw = (wv >> 1) * 64, nw = (wv & 1) * 64;
    int m16 = lane & 15, quad = lane >> 4;
    int srow = tid >> 1, shalf = tid & 1;

    f4_t acc[4][4];
    #pragma unroll
    for (int i = 0; i < 4; i++)
        #pragma unroll
        for (int j = 0; j < 4; j++)
            acc[i][j] = (f4_t){0.f, 0.f, 0.f, 0.f};

    for (int k0 = 0; k0 < KTOT; k0 += 64) {
        {
            const uint4* ap = (const uint4*)&A[(size_t)(m0 + srow) * KTOT + k0 + shalf * 32];
            uint4 a0 = ap[0], a1 = ap[1], a2 = ap[2], a3 = ap[3];
            uint4* dst = (uint4*)&As[srow][shalf * 32];
            dst[0] = a0; dst[1] = a1; dst[2] = a2; dst[3] = a3;
        }
        {
            int n = n0 + srow;
            uint4 q[4];
            if (n < V) {
                const float4* bp = (const float4*)&Wo[(size_t)n * KTOT + k0 + shalf * 32];
                #pragma unroll
                for (int g = 0; g < 4; g++) {
                    float4 f0 = bp[g * 2], f1 = bp[g * 2 + 1];
                    q[g].x = ((unsigned int)f2bf(f0.y) << 16) | f2bf(f0.x);
                    q[g].y = ((unsigned int)f2bf(f0.w) << 16) | f2bf(f0.z);
                    q[g].z = ((unsigned int)f2bf(f1.y) << 16) | f2bf(f1.x);
                    q[g].w = ((unsigned int)f2bf(f1.w) << 16) | f2bf(f1.z);
                }
            } else {
                #pragma unroll
                for (int g = 0; g < 4; g++) q[g] = (uint4){0u, 0u, 0u, 0u};
            }
            uint4* dst = (uint4*)&Bs[srow][shalf * 32];
            #pragma unroll
            for (int g = 0; g < 4; g++) dst[g] = q[g];
        }
        __syncthreads();
        #pragma unroll
        for (int h = 0; h < 2; h++) {
            bf8_t af[4], bf[4];
            #pragma unroll
            for (int i = 0; i < 4; i++)
                af[i] = *(const bf8_t*)&As[mw + i * 16 + m16][h * 32 + quad * 8];
            #pragma unroll
            for (int j = 0; j < 4; j++)
                bf[j] = *(const bf8_t*)&Bs[nw + j * 16 + m16][h * 32 + quad * 8];
            #pragma unroll
            for (int i = 0; i < 4; i++)
                #pragma unroll
                for (int j = 0; j < 4; j++)
                    acc[i][j] = __builtin_amdgcn_mfma_f32_16x16x32_bf16(af[i], bf[j], acc[i][j], 0, 0, 0);
        }
        __syncthreads();
    }

    #pragma unroll
    for (int j = 0; j < 4; j++) {
        int n = n0 + nw + j * 16 + m16;
        if (n >= V) continue;
        float bias = bo[n];
        #pragma unroll
        for (int i = 0; i < 4; i++) {
            int mb = m0 + mw + i * 16 + quad * 4;
            #pragma unroll
            for (int r = 0; r < 4; r++)
                Cout[(size_t)(mb + r) * V + n] = acc[i][j][r] + bias;
        }
    }
}

// ---------- logits: bf16 MFMA with pre-converted bf16 B ----------
__global__ __launch_bounds__(256) void k_logits5(
    const unsigned short* __restrict__ A, const unsigned short* __restrict__ Wob,
    const float* __restrict__ bo, float* __restrict__ Cout) {
    __shared__ unsigned short As[128][72];
    __shared__ unsigned short Bs[128][72];
    int n0 = blockIdx.x * 128;
    int m0 = blockIdx.y * 128;
    int tid = threadIdx.x;
    int lane = tid & 63, wv = tid >> 6;
    int mw = (wv >> 1) * 64, nw = (wv & 1) * 64;
    int m16 = lane & 15, quad = lane >> 4;
    int srow = tid >> 1, shalf = tid & 1;

    f4_t acc[4][4];
    #pragma unroll
    for (int i = 0; i < 4; i++)
        #pragma unroll
        for (int j = 0; j < 4; j++)
            acc[i][j] = (f4_t){0.f, 0.f, 0.f, 0.f};

    for (int k0 = 0; k0 < KTOT; k0 += 64) {
        {
            const uint4* ap = (const uint4*)&A[(size_t)(m0 + srow) * KTOT + k0 + shalf * 32];
            uint4 a0 = ap[0], a1 = ap[1], a2 = ap[2], a3 = ap[3];
            uint4* dst = (uint4*)&As[srow][shalf * 32];
            dst[0] = a0; dst[1] = a1; dst[2] = a2; dst[3] = a3;
        }
        {
            int n = n0 + srow;
            uint4 q[4];
            if (n < V) {
                const uint4* bp = (const uint4*)&Wob[(size_t)n * KTOT + k0 + shalf * 32];
                #pragma unroll
                for (int g = 0; g < 4; g++) q[g] = bp[g];
            } else {
                #pragma unroll
                for (int g = 0; g < 4; g++) q[g] = (uint4){0u, 0u, 0u, 0u};
            }
            uint4* dst = (uint4*)&Bs[srow][shalf * 32];
            #pragma unroll
            for (int g = 0; g < 4; g++) dst[g] = q[g];
        }
        __syncthreads();
        #pragma unroll
        for (int h = 0; h < 2; h++) {
            bf8_t af[4], bf[4];
            #pragma unroll
            for (int i = 0; i < 4; i++)
                af[i] = *(const bf8_t*)&As[mw + i * 16 + m16][h * 32 + quad * 8];
            #pragma unroll
            for (int j = 0; j < 4; j++)
                bf[j] = *(const bf8_t*)&Bs[nw + j * 16 + m16][h * 32 + quad * 8];
            #pragma unroll
            for (int i = 0; i < 4; i++)
                #pragma unroll
                for (int j = 0; j < 4; j++)
                    acc[i][j] = __builtin_amdgcn_mfma_f32_16x16x32_bf16(af[i], bf[j], acc[i][j], 0, 0, 0);
        }
        __syncthreads();
    }

    #pragma unroll
    for (int j = 0; j < 4; j++) {
        int n = n0 + nw + j * 16 + m16;
        if (n >= V) continue;
        float bias = bo[n];
        #pragma unroll
        for (int i = 0; i < 4; i++) {
            int mb = m0 + mw + i * 16 + quad * 4;
            #pragma unroll
            for (int r = 0; r < 4; r++)
                Cout[(size_t)(mb + r) * V + n] = acc[i][j][r] + bias;
        }
    }
}

extern "C" void kernel_launch(void* const* d_in, const int* in_sizes, int n_in,
                              void* d_out, int out_size, void* d_ws, size_t ws_size,
                              hipStream_t stream) {
    const float* img   = (const float*)d_in[0];
    const int*   capix = (const int*)d_in[1];
    const float* W_h0  = (const float*)d_in[2];
    const float* b_h0  = (const float*)d_in[3];
    const float* W_c0  = (const float*)d_in[4];
    const float* b_c0  = (const float*)d_in[5];
    const float* emb   = (const float*)d_in[6];
    const float* W_key = (const float*)d_in[7];
    const float* b_key = (const float*)d_in[8];
    const float* W_ih  = (const float*)d_in[9];
    const float* b_ih  = (const float*)d_in[10];
    const float* W_hh  = (const float*)d_in[11];
    const float* b_hh  = (const float*)d_in[12];
    const float* W_out = (const float*)d_in[13];
    const float* b_out = (const float*)d_in[14];

    float* ws = (float*)d_ws;
    float* gates4    = ws;                        // 131072 f (fm overlaid)
    float* fm        = ws;                        // 32768 f, dead before t=0 gates
    float* cell      = gates4 + 131072;           // 32768 f
    float* WkT       = cell + 32768;              // 262144 f; dead after k_keys ->
    int*   barf      = (int*)WkT;                 //   reused as barrier flags
    unsigned short* Wg    = (unsigned short*)(WkT + 262144);  // 2621440 ush
    unsigned short* xb    = Wg + 2621440;                      // 81920 ush
    unsigned short* outs  = xb + 81920;                        // 1638400 ush
    unsigned short* keys2 = outs + (size_t)B * T * ODIM;       // 6422528 ush
    const size_t IMG2_OFF = 23232576;                          // 64B-aligned
    unsigned short* img2 = (unsigned short*)((char*)d_ws + IMG2_OFF);
    bool use_img2 = ws_size >= IMG2_OFF + (size_t)B * C * 200 * 2;   // 36,339,776
    const size_t WOB_OFF = 36339776;                           // 64B-aligned
    unsigned short* Wob = (unsigned short*)((char*)d_ws + WOB_OFF);
    bool use_wob = ws_size >= WOB_OFF + (size_t)V * KTOT * 2;  // 61,939,776

    float* logits = (float*)d_out;
    float* attn   = logits + (size_t)B * T * V;

    k_mean<<<(B * C) / 4, 256, 0, stream>>>(img, fm);
    k_init<<<(2 * B * U) / 4, 256, 0, stream>>>(fm, W_h0, b_h0, W_c0, b_c0, xb, cell);
    k_wkt<<<dim3(8, 8), 256, 0, stream>>>(W_key, WkT);
    k_keys<<<B * 16, 256, 0, stream>>>(img, WkT, b_key, keys2);
    k_wg<<<G4U, 256, 0, stream>>>(W_ih, W_hh, Wg);
    k_emb<<<B * T, 256, 0, stream>>>(capix, emb, outs, barf);
    if (use_img2)
        k_img<<<3200, 256, 0, stream>>>(img, img2);
    if (use_wob)
        k_wo<<<(V * KTOT) / 2048, 256, 0, stream>>>(W_out, Wob);

    k_loop<<<NBLK, 512, 0, stream>>>(outs, xb, cell, gates4, keys2, img,
                                     use_img2 ? img2 : (const unsigned short*)nullptr,
                                     b_ih, b_hh, Wg, attn, barf);

    if (use_wob)
        k_logits5<<<dim3((V + 127) / 128, (B * T) / 128), 256, 0, stream>>>(outs, Wob, b_out, logits);
    else
        k_logits4<<<dim3((V + 127) / 128, (B * T) / 128), 256, 0, stream>>>(outs, W_out, b_out, logits);
}